// Round 7
// baseline (402.798 us; speedup 1.0000x reference)
//
#include <hip/hip_runtime.h>
#include <math.h>

#define N_NODE 100000
#define N_EDGE 1600000
#define D_FEAT 64
#define DEPTH  3
#define OUT_STRIDE ((DEPTH + 1) * D_FEAT)   // 256 floats per node row

// ---- bucketed CSR build ----------------------------------------------------
#define NB  256                      // coarse buckets
#define RPB 391                      // rows per bucket: 256*391 = 100096 >= N
#define CAP 8192                     // per-bucket edge capacity (mean 6250, +24 sigma)
#define S1_BS 512
#define S1_CHUNK 8192                // edges per stage1 block
#define S1_BLOCKS ((N_EDGE + S1_CHUNK - 1) / S1_CHUNK)   // 196

// ---- column-octant grouping (kept from r5; harmless) -----------------------
#define NOCT 16
#define OCT_DIV 6250
#define NCELL (RPB * NOCT)           // 6256
#define NCHUNK (NCELL / 8)           // 782

// ---- feature-split spmm (4 nodes x 16 feats per wave) -----------------------
#define PASSES 4
#define FPP    16                    // feats/pass; slice = N*FPP*2B = 3.2MB < L2
#define NODES_PER_BLOCK 16           // 4 waves x 4 nodes
#define BPP (N_NODE / NODES_PER_BLOCK)          // 6250 blocks per pass

// fixed-point scale for weighted-degree accumulation (ea in [0,1), deg < 128)
#define DEG_SCALE 33554432.0f        // 2^25

typedef float  f32x4 __attribute__((ext_vector_type(4)));

__device__ __forceinline__ unsigned int bf16_rne(float f) {
    unsigned int u = __float_as_uint(f);
    return (u + 0x7FFFu + ((u >> 16) & 1u)) >> 16;
}

// ---------------------------------------------------------------------------
// 1. multisplit edges into NB buckets (contiguous segment reservation).
__global__ __launch_bounds__(S1_BS) void stage1_bucket(
        const int* __restrict__ ei, const float* __restrict__ ea,
        int* __restrict__ bucket_cursor, int2* __restrict__ bucket) {
    __shared__ int hist[NB];
    __shared__ int segb[NB];
    int tid = threadIdx.x;
    int e0 = blockIdx.x * S1_CHUNK;

    for (int i = tid; i < NB; i += S1_BS) hist[i] = 0;
    __syncthreads();

    for (int k = 0; k < S1_CHUNK; k += S1_BS) {
        int e = e0 + k + tid;
        if (e < N_EDGE) {
            int r = ei[e];
            atomicAdd(&hist[r / RPB], 1);
        }
    }
    __syncthreads();

    for (int i = tid; i < NB; i += S1_BS) {
        int h = hist[i];
        segb[i] = (h > 0) ? atomicAdd(&bucket_cursor[i], h) : 0;
        hist[i] = 0;
    }
    __syncthreads();

    for (int k = 0; k < S1_CHUNK; k += S1_BS) {
        int e = e0 + k + tid;
        if (e < N_EDGE) {
            int r  = ei[e];
            int b  = r / RPB;
            int rl = r - b * RPB;         // 9 bits
            int c  = ei[N_EDGE + e];      // 17 bits
            float w = ea[e];
            int lofs = atomicAdd(&hist[b], 1);
            int pos  = segb[b] + lofs;
            if (pos < CAP)
                bucket[(size_t)b * CAP + pos] =
                    make_int2((rl << 17) | c, __float_as_int(w));
        }
    }
}

// ---------------------------------------------------------------------------
// 2. exclusive scan of NB bucket counts -> CSR bucket bases; a[L]=tanh(alpha)
__global__ void bucket_scan_kernel(const int* __restrict__ bucket_cursor,
                                   int* __restrict__ bucket_base,
                                   const float* __restrict__ alphas,
                                   float* __restrict__ a_vals) {
    __shared__ int sc[NB];
    int tid = threadIdx.x;               // 256 threads
    int v = bucket_cursor[tid];
    sc[tid] = v;
    __syncthreads();
    for (int off = 1; off < NB; off <<= 1) {
        int t = (tid >= off) ? sc[tid - off] : 0;
        __syncthreads();
        sc[tid] += t;
        __syncthreads();
    }
    bucket_base[tid] = sc[tid] - v;      // exclusive
    if (tid < DEPTH + 1) a_vals[tid] = tanhf(alphas[tid]);
}

// ---------------------------------------------------------------------------
// 3. fused per-bucket CSR build with (row, col-octant) grouping.
__global__ __launch_bounds__(1024) void stage2_fused(
        const int2* __restrict__ bucket, const int* __restrict__ bucket_cnt,
        const int* __restrict__ bucket_base,
        int* __restrict__ row_ptr, int* __restrict__ row_end,
        float* __restrict__ dinv, int2* __restrict__ csr) {
    __shared__ int          cnt2[NCELL];
    __shared__ unsigned int wdeg[RPB];
    __shared__ int          sc[1024];
    __shared__ int2         staged[CAP];     // 64 KB
    int b = blockIdx.x, tid = threadIdx.x;

    for (int i = tid; i < NCELL; i += 1024) cnt2[i] = 0;
    if (tid < RPB) wdeg[tid] = 0u;
    __syncthreads();

    int cnt = bucket_cnt[b];
    const int2* src = bucket + (size_t)b * CAP;

    for (int i = tid; i < cnt; i += 1024) {
        int2 e = src[i];
        int rl = e.x >> 17;
        int c  = e.x & 0x1FFFF;
        int oc = c / OCT_DIV;
        atomicAdd(&cnt2[rl * NOCT + oc], 1);
        atomicAdd(&wdeg[rl],
                  (unsigned int)(__int_as_float(e.y) * DEG_SCALE + 0.5f));
    }
    __syncthreads();

    int lsum = 0;
    if (tid < NCHUNK) {
        int base = tid * 8;
        #pragma unroll
        for (int j = 0; j < 8; ++j) lsum += cnt2[base + j];
    }
    sc[tid] = lsum;
    __syncthreads();
    for (int off = 1; off < 1024; off <<= 1) {
        int t = (tid >= off) ? sc[tid - off] : 0;
        __syncthreads();
        sc[tid] += t;
        __syncthreads();
    }
    if (tid < NCHUNK) {
        int run = sc[tid] - lsum;
        int base = tid * 8;
        #pragma unroll
        for (int j = 0; j < 8; ++j) {
            int v = cnt2[base + j];
            cnt2[base + j] = run;
            run += v;
        }
    }
    __syncthreads();

    int base_b = bucket_base[b];
    if (tid < RPB) {
        int row = b * RPB + tid;
        if (row < N_NODE) {
            int rb = cnt2[tid * NOCT];
            int re = (tid == RPB - 1) ? cnt : cnt2[(tid + 1) * NOCT];
            row_ptr[row] = base_b + rb;
            row_end[row] = base_b + re;
            float d = (float)wdeg[tid] * (1.0f / DEG_SCALE);
            dinv[row] = (d > 0.0f) ? rsqrtf(d) : 0.0f;
        }
    }
    __syncthreads();

    for (int i = tid; i < cnt; i += 1024) {
        int2 e = src[i];
        int rl = e.x >> 17;
        int c  = e.x & 0x1FFFF;
        int oc = c / OCT_DIV;
        int pos = atomicAdd(&cnt2[rl * NOCT + oc], 1);
        staged[pos] = make_int2(c, e.y);    // keep raw w
    }
    __syncthreads();

    for (int i = tid; i < cnt; i += 1024) csr[base_b + i] = staged[i];
}

// ---------------------------------------------------------------------------
// 4. out[n,0,d] = x[n,d] (exact, nt store); bf16 shadow hb0 PASS-MAJOR:
//    hb0[(pass*N + n)*FPP + f] = bf16(dinv[n]*x[n][pass*FPP+f])
__global__ void init_out_kernel(const float* __restrict__ x,
                                const float* __restrict__ dinv,
                                float* __restrict__ out,
                                unsigned short* __restrict__ hb0,
                                int write_hb) {
    int i = blockIdx.x * blockDim.x + threadIdx.x;   // one per 4 feats
    if (i < N_NODE * (D_FEAT / 4)) {
        int n  = i >> 4;
        int d4 = (i & 15) << 2;
        float4 v = *(const float4*)&x[(size_t)n * D_FEAT + d4];
        f32x4 vv = {v.x, v.y, v.z, v.w};
        __builtin_nontemporal_store(
            vv, (f32x4*)&out[(size_t)n * OUT_STRIDE + d4]);
        if (write_hb) {
            float s = dinv[n];
            int pass = d4 >> 4;
            int fo   = d4 & 15;
            uint2 o;
            o.x = bf16_rne(v.x * s) | (bf16_rne(v.y * s) << 16);
            o.y = bf16_rne(v.z * s) | (bf16_rne(v.w * s) << 16);
            *(uint2*)&hb0[((size_t)pass * N_NODE + n) * FPP + fo] = o;
        }
    }
}

// ---------------------------------------------------------------------------
// 5a. feature-split gather SpMM, SAME wave count as the full-D version:
//     wave = 4 nodes x 16 feats (pass slice). 16 lanes per node =
//     8 edge-subgroups x 2 feat-lanes (uint4 = 8 bf16 each).
//     Pass-major grid: co-running blocks share one 3.2MB L2-resident slice.
//     out_L[i] = aL*dinv_i * sum w_e*g[col_e];  g_L[i] = dinv_i*out_L[i]
__global__ __launch_bounds__(256) void spmm_bf16_kernel(
        const int* __restrict__ row_ptr,
        const int* __restrict__ row_end,
        const int2* __restrict__ csr,
        const float* __restrict__ a_vals,
        const float* __restrict__ dinv,
        const unsigned short* __restrict__ hsrc,
        unsigned short* __restrict__ hdst,
        float* __restrict__ out,
        int L, int write_hdst) {
    int pass = blockIdx.x / BPP;
    int nb   = blockIdx.x - pass * BPP;
    int lane = threadIdx.x & 63;
    int grp  = lane >> 4;                     // node sub-index 0..3
    int node = nb * NODES_PER_BLOCK + (threadIdx.x >> 6) * 4 + grp;
    int l16  = lane & 15;
    int s    = l16 >> 1;                      // edge subgroup 0..7
    int f    = l16 & 1;                       // feature half (8 feats)

    int beg = row_ptr[node];
    int end = row_end[node];

    const unsigned short* slab = hsrc + (size_t)pass * N_NODE * FPP;

    float acc[8] = {0, 0, 0, 0, 0, 0, 0, 0};

    for (int chunk = beg; chunk < end; chunk += 16) {
        int idx = chunk + l16;
        int2 pv = make_int2(0, 0);
        if (idx < end) {
            long long t =
                __builtin_nontemporal_load((const long long*)(csr + idx));
            pv = *(int2*)&t;
        }
        int navail = end - chunk;
        if (navail > 16) navail = 16;
        for (int t = 0; t < navail; t += 8) {
            int sub = t + s;
            int   cc = __shfl(pv.x, sub, 16);
            float vv = __int_as_float(__shfl(pv.y, sub, 16));
            bool valid = (sub < navail);
            int   c_safe = valid ? cc : 0;
            float v_safe = valid ? vv : 0.0f;
            uint4 hv = *(const uint4*)&slab[(size_t)c_safe * FPP + (f << 3)];
            acc[0] += v_safe * __uint_as_float((hv.x & 0xFFFFu) << 16);
            acc[1] += v_safe * __uint_as_float(hv.x & 0xFFFF0000u);
            acc[2] += v_safe * __uint_as_float((hv.y & 0xFFFFu) << 16);
            acc[3] += v_safe * __uint_as_float(hv.y & 0xFFFF0000u);
            acc[4] += v_safe * __uint_as_float((hv.z & 0xFFFFu) << 16);
            acc[5] += v_safe * __uint_as_float(hv.z & 0xFFFF0000u);
            acc[6] += v_safe * __uint_as_float((hv.w & 0xFFFFu) << 16);
            acc[7] += v_safe * __uint_as_float(hv.w & 0xFFFF0000u);
        }
    }

    // fold the 8 edge-subgroups (stride-2 lanes) into l16 = {0,1}
    #pragma unroll
    for (int j = 0; j < 8; ++j) {
        acc[j] += __shfl_down(acc[j], 8);
        acc[j] += __shfl_down(acc[j], 4);
        acc[j] += __shfl_down(acc[j], 2);
    }

    if (l16 < 2) {
        float di = dinv[node];
        float aL = a_vals[L];
        float s1 = aL * di;          // out scale
        float s2 = s1 * di;          // next-shadow scale
        f32x4 r0 = {s1 * acc[0], s1 * acc[1], s1 * acc[2], s1 * acc[3]};
        f32x4 r1 = {s1 * acc[4], s1 * acc[5], s1 * acc[6], s1 * acc[7]};
        // 2 lanes x 32B = one 64B line per node
        size_t ob = (size_t)node * OUT_STRIDE + L * D_FEAT + pass * FPP
                  + (f << 3);
        __builtin_nontemporal_store(r0, (f32x4*)&out[ob]);
        __builtin_nontemporal_store(r1, (f32x4*)&out[ob + 4]);
        if (write_hdst) {
            uint4 o;
            o.x = bf16_rne(s2 * acc[0]) | (bf16_rne(s2 * acc[1]) << 16);
            o.y = bf16_rne(s2 * acc[2]) | (bf16_rne(s2 * acc[3]) << 16);
            o.z = bf16_rne(s2 * acc[4]) | (bf16_rne(s2 * acc[5]) << 16);
            o.w = bf16_rne(s2 * acc[6]) | (bf16_rne(s2 * acc[7]) << 16);
            // pass-major: 2 lanes x 16B, 4 consecutive nodes => 128B contiguous
            *(uint4*)&hdst[((size_t)pass * N_NODE + node) * FPP + (f << 3)] = o;
        }
    }
}

// 5b. fallback fp32-source gather (used only if ws too small for shadows).
__global__ void spmm_f32_kernel(const int* __restrict__ row_ptr,
                                const int* __restrict__ row_end,
                                const int2* __restrict__ csr,
                                const float* __restrict__ a_vals,
                                const float* __restrict__ dinv,
                                float* __restrict__ out,
                                int L) {
    int node = blockIdx.x * (blockDim.x >> 6) + (threadIdx.x >> 6);
    int lane = threadIdx.x & 63;
    if (node >= N_NODE) return;
    int beg = row_ptr[node];
    int end = row_end[node];
    int g = lane >> 4;
    int q = lane & 15;
    int src_base = (L - 1) * D_FEAT + (q << 2);

    float4 acc = make_float4(0.0f, 0.0f, 0.0f, 0.0f);
    for (int chunk = beg; chunk < end; chunk += 64) {
        int idx = chunk + lane;
        int2 pv = (idx < end) ? csr[idx] : make_int2(0, 0);
        int navail = end - chunk;
        if (navail > 64) navail = 64;
        for (int t = 0; t < navail; t += 4) {
            int sub = t + g;
            int   cc = __shfl(pv.x, sub);
            float vv = __int_as_float(__shfl(pv.y, sub));
            bool valid = (sub < navail);
            int   c_safe = valid ? cc : 0;
            float v_safe = valid ? (vv * dinv[c_safe]) : 0.0f;
            const float4 hv =
                *(const float4*)&out[(size_t)c_safe * OUT_STRIDE + src_base];
            acc.x += v_safe * hv.x;
            acc.y += v_safe * hv.y;
            acc.z += v_safe * hv.z;
            acc.w += v_safe * hv.w;
        }
    }
    acc.x += __shfl_down(acc.x, 32);
    acc.y += __shfl_down(acc.y, 32);
    acc.z += __shfl_down(acc.z, 32);
    acc.w += __shfl_down(acc.w, 32);
    acc.x += __shfl_down(acc.x, 16);
    acc.y += __shfl_down(acc.y, 16);
    acc.z += __shfl_down(acc.z, 16);
    acc.w += __shfl_down(acc.w, 16);
    if (g == 0) {
        float s1 = a_vals[L] * dinv[node];
        float4 r = make_float4(s1 * acc.x, s1 * acc.y, s1 * acc.z, s1 * acc.w);
        *(float4*)&out[(size_t)node * OUT_STRIDE + L * D_FEAT + (q << 2)] = r;
    }
}

// ---------------------------------------------------------------------------
extern "C" void kernel_launch(void* const* d_in, const int* in_sizes, int n_in,
                              void* d_out, int out_size, void* d_ws, size_t ws_size,
                              hipStream_t stream) {
    const float* x      = (const float*)d_in[0];
    const int*   ei     = (const int*)d_in[1];   // [2, E] int32
    const float* ea     = (const float*)d_in[2];
    const float* alphas = (const float*)d_in[3];
    float*       out    = (float*)d_out;

    // workspace layout (bucket store aliases the bf16 shadows)
    int2*  csr          = (int2*)d_ws;                       // E     (12.8 MB)
    int*   row_ptr      = (int*)(csr + N_EDGE);              // N
    int*   row_end      = row_ptr + N_NODE;                  // N
    float* dinv         = (float*)(row_end + N_NODE);        // N
    int*   bucket_cursor= (int*)(dinv + N_NODE);             // NB
    int*   bucket_base  = bucket_cursor + NB;                // NB
    float* a_vals       = (float*)(bucket_base + NB);        // 4
    int2*  bucket       = (int2*)(a_vals + 4);               // NB*CAP (16.8 MB)
    unsigned short* hb0 = (unsigned short*)bucket;           // union w/ bucket
    unsigned short* hb1 = hb0 + (size_t)N_NODE * D_FEAT;

    size_t base_bytes = (size_t)((char*)bucket - (char*)d_ws);
    size_t need_bf16  = base_bytes +
        2 * (size_t)N_NODE * D_FEAT * sizeof(unsigned short);   // ~39.7 MB
    int use_bf16 = (ws_size >= need_bf16) ? 1 : 0;

    hipMemsetAsync(bucket_cursor, 0, NB * sizeof(int), stream);

    stage1_bucket<<<S1_BLOCKS, S1_BS, 0, stream>>>(ei, ea, bucket_cursor, bucket);
    bucket_scan_kernel<<<1, NB, 0, stream>>>(bucket_cursor, bucket_base,
                                             alphas, a_vals);
    stage2_fused<<<NB, 1024, 0, stream>>>(bucket, bucket_cursor, bucket_base,
                                          row_ptr, row_end, dinv, csr);
    init_out_kernel<<<(N_NODE * (D_FEAT / 4) + 255) / 256, 256, 0, stream>>>(
        x, dinv, out, hb0, use_bf16);

    if (use_bf16) {
        int grid = PASSES * BPP;     // pass-major: 4 x 6250 blocks
        spmm_bf16_kernel<<<grid, 256, 0, stream>>>(row_ptr, row_end, csr,
            a_vals, dinv, hb0, hb1, out, 1, 1);
        spmm_bf16_kernel<<<grid, 256, 0, stream>>>(row_ptr, row_end, csr,
            a_vals, dinv, hb1, hb0, out, 2, 1);
        spmm_bf16_kernel<<<grid, 256, 0, stream>>>(row_ptr, row_end, csr,
            a_vals, dinv, hb0, hb1, out, 3, 0);
    } else {
        int nodes_per_block = 256 / 64;
        int spmm_blocks = (N_NODE + nodes_per_block - 1) / nodes_per_block;
        for (int L = 1; L <= DEPTH; ++L) {
            spmm_f32_kernel<<<spmm_blocks, 256, 0, stream>>>(row_ptr, row_end, csr,
                a_vals, dinv, out, L);
        }
    }
}

// Round 8
// 322.427 us; speedup vs baseline: 1.2493x; 1.2493x over previous
//
#include <hip/hip_runtime.h>
#include <math.h>

#define N_NODE 100000
#define N_EDGE 1600000
#define D_FEAT 64
#define DEPTH  3
#define OUT_STRIDE ((DEPTH + 1) * D_FEAT)   // 256 floats per node row

// ---- bucketed CSR build ----------------------------------------------------
#define NB  256                      // coarse buckets
#define RPB 391                      // rows per bucket: 256*391 = 100096 >= N
#define CAP 8192                     // per-bucket edge capacity (mean 6250, +24 sigma)
#define S1_BS 512
#define S1_CHUNK 8192                // edges per stage1 block
#define S1_BLOCKS ((N_EDGE + S1_CHUNK - 1) / S1_CHUNK)   // 196

// ---- column-octant grouping (kept; neutral, low-risk) ----------------------
#define NOCT 16
#define OCT_DIV 6250
#define NCELL (RPB * NOCT)           // 6256
#define NCHUNK (NCELL / 8)           // 782

// ---- lane-owns-feature spmm -------------------------------------------------
#define SPMM_NPB 16                  // nodes per 256-thread block (4/wave)
#define SPMM_BLOCKS (N_NODE / SPMM_NPB)      // 6250

// fixed-point scale for weighted-degree accumulation (ea in [0,1), deg < 128)
#define DEG_SCALE 33554432.0f        // 2^25

typedef float  f32x4 __attribute__((ext_vector_type(4)));

__device__ __forceinline__ unsigned int bf16_rne(float f) {
    unsigned int u = __float_as_uint(f);
    return (u + 0x7FFFu + ((u >> 16) & 1u)) >> 16;
}

// ---------------------------------------------------------------------------
// 1. multisplit edges into NB buckets (contiguous segment reservation).
__global__ __launch_bounds__(S1_BS) void stage1_bucket(
        const int* __restrict__ ei, const float* __restrict__ ea,
        int* __restrict__ bucket_cursor, int2* __restrict__ bucket) {
    __shared__ int hist[NB];
    __shared__ int segb[NB];
    int tid = threadIdx.x;
    int e0 = blockIdx.x * S1_CHUNK;

    for (int i = tid; i < NB; i += S1_BS) hist[i] = 0;
    __syncthreads();

    for (int k = 0; k < S1_CHUNK; k += S1_BS) {
        int e = e0 + k + tid;
        if (e < N_EDGE) {
            int r = ei[e];
            atomicAdd(&hist[r / RPB], 1);
        }
    }
    __syncthreads();

    for (int i = tid; i < NB; i += S1_BS) {
        int h = hist[i];
        segb[i] = (h > 0) ? atomicAdd(&bucket_cursor[i], h) : 0;
        hist[i] = 0;
    }
    __syncthreads();

    for (int k = 0; k < S1_CHUNK; k += S1_BS) {
        int e = e0 + k + tid;
        if (e < N_EDGE) {
            int r  = ei[e];
            int b  = r / RPB;
            int rl = r - b * RPB;         // 9 bits
            int c  = ei[N_EDGE + e];      // 17 bits
            float w = ea[e];
            int lofs = atomicAdd(&hist[b], 1);
            int pos  = segb[b] + lofs;
            if (pos < CAP)
                bucket[(size_t)b * CAP + pos] =
                    make_int2((rl << 17) | c, __float_as_int(w));
        }
    }
}

// ---------------------------------------------------------------------------
// 2. exclusive scan of NB bucket counts -> CSR bucket bases; a[L]=tanh(alpha)
__global__ void bucket_scan_kernel(const int* __restrict__ bucket_cursor,
                                   int* __restrict__ bucket_base,
                                   const float* __restrict__ alphas,
                                   float* __restrict__ a_vals) {
    __shared__ int sc[NB];
    int tid = threadIdx.x;               // 256 threads
    int v = bucket_cursor[tid];
    sc[tid] = v;
    __syncthreads();
    for (int off = 1; off < NB; off <<= 1) {
        int t = (tid >= off) ? sc[tid - off] : 0;
        __syncthreads();
        sc[tid] += t;
        __syncthreads();
    }
    bucket_base[tid] = sc[tid] - v;      // exclusive
    if (tid < DEPTH + 1) a_vals[tid] = tanhf(alphas[tid]);
}

// ---------------------------------------------------------------------------
// 3. fused per-bucket CSR build with (row, col-octant) grouping.
__global__ __launch_bounds__(1024) void stage2_fused(
        const int2* __restrict__ bucket, const int* __restrict__ bucket_cnt,
        const int* __restrict__ bucket_base,
        int* __restrict__ row_ptr, int* __restrict__ row_end,
        float* __restrict__ dinv, int2* __restrict__ csr) {
    __shared__ int          cnt2[NCELL];
    __shared__ unsigned int wdeg[RPB];
    __shared__ int          sc[1024];
    __shared__ int2         staged[CAP];     // 64 KB
    int b = blockIdx.x, tid = threadIdx.x;

    for (int i = tid; i < NCELL; i += 1024) cnt2[i] = 0;
    if (tid < RPB) wdeg[tid] = 0u;
    __syncthreads();

    int cnt = bucket_cnt[b];
    const int2* src = bucket + (size_t)b * CAP;

    for (int i = tid; i < cnt; i += 1024) {
        int2 e = src[i];
        int rl = e.x >> 17;
        int c  = e.x & 0x1FFFF;
        int oc = c / OCT_DIV;
        atomicAdd(&cnt2[rl * NOCT + oc], 1);
        atomicAdd(&wdeg[rl],
                  (unsigned int)(__int_as_float(e.y) * DEG_SCALE + 0.5f));
    }
    __syncthreads();

    int lsum = 0;
    if (tid < NCHUNK) {
        int base = tid * 8;
        #pragma unroll
        for (int j = 0; j < 8; ++j) lsum += cnt2[base + j];
    }
    sc[tid] = lsum;
    __syncthreads();
    for (int off = 1; off < 1024; off <<= 1) {
        int t = (tid >= off) ? sc[tid - off] : 0;
        __syncthreads();
        sc[tid] += t;
        __syncthreads();
    }
    if (tid < NCHUNK) {
        int run = sc[tid] - lsum;
        int base = tid * 8;
        #pragma unroll
        for (int j = 0; j < 8; ++j) {
            int v = cnt2[base + j];
            cnt2[base + j] = run;
            run += v;
        }
    }
    __syncthreads();

    int base_b = bucket_base[b];
    if (tid < RPB) {
        int row = b * RPB + tid;
        if (row < N_NODE) {
            int rb = cnt2[tid * NOCT];
            int re = (tid == RPB - 1) ? cnt : cnt2[(tid + 1) * NOCT];
            row_ptr[row] = base_b + rb;
            row_end[row] = base_b + re;
            float d = (float)wdeg[tid] * (1.0f / DEG_SCALE);
            dinv[row] = (d > 0.0f) ? rsqrtf(d) : 0.0f;
        }
    }
    __syncthreads();

    for (int i = tid; i < cnt; i += 1024) {
        int2 e = src[i];
        int rl = e.x >> 17;
        int c  = e.x & 0x1FFFF;
        int oc = c / OCT_DIV;
        int pos = atomicAdd(&cnt2[rl * NOCT + oc], 1);
        staged[pos] = make_int2(c, e.y);    // keep raw w
    }
    __syncthreads();

    for (int i = tid; i < cnt; i += 1024) csr[base_b + i] = staged[i];
}

// ---------------------------------------------------------------------------
// 4. out[n,0,d] = x[n,d] (exact, nt store); bf16 shadow hb0 = bf16(dinv*x)
__global__ void init_out_kernel(const float* __restrict__ x,
                                const float* __restrict__ dinv,
                                float* __restrict__ out,
                                unsigned short* __restrict__ hb0,
                                int write_hb) {
    int i = blockIdx.x * blockDim.x + threadIdx.x;   // one per 4 feats
    if (i < N_NODE * (D_FEAT / 4)) {
        int n  = i >> 4;
        int d4 = (i & 15) << 2;
        float4 v = *(const float4*)&x[(size_t)n * D_FEAT + d4];
        f32x4 vv = {v.x, v.y, v.z, v.w};
        __builtin_nontemporal_store(
            vv, (f32x4*)&out[(size_t)n * OUT_STRIDE + d4]);
        if (write_hb) {
            float s = dinv[n];
            uint2 o;
            o.x = bf16_rne(v.x * s) | (bf16_rne(v.y * s) << 16);
            o.y = bf16_rne(v.z * s) | (bf16_rne(v.w * s) << 16);
            *(uint2*)&hb0[(size_t)n * D_FEAT + d4] = o;
        }
    }
}

// ---------------------------------------------------------------------------
// 5a. lane-owns-feature gather SpMM (full D, bf16 dinv-scaled source).
//     wave = 4 nodes x 16 lanes; lane owns feats [4*l16 .. 4*l16+3] (uint2).
//     Per edge: 2 width-16 shuffles broadcast (c,w); each lane issues one
//     independent 8B gather -> 16 lanes cover the 128B row exactly; no
//     cross-lane reduction at all. ~16-22 loads in flight per wave.
//     out_L[i] = aL*dinv_i * sum w_e*g[col_e];  g_L[i] = dinv_i*out_L[i]
__global__ __launch_bounds__(256) void spmm_bf16_kernel(
        const int* __restrict__ row_ptr,
        const int* __restrict__ row_end,
        const int2* __restrict__ csr,
        const float* __restrict__ a_vals,
        const float* __restrict__ dinv,
        const unsigned short* __restrict__ hsrc,
        unsigned short* __restrict__ hdst,
        float* __restrict__ out,
        int L, int write_hdst) {
    int wid  = threadIdx.x >> 6;              // wave 0..3
    int lane = threadIdx.x & 63;
    int grp  = lane >> 4;                     // node sub-index 0..3
    int l16  = lane & 15;                     // feature quad 0..15
    int node = blockIdx.x * SPMM_NPB + wid * 4 + grp;
    unsigned int fo = (unsigned int)(l16 << 2);   // feat offset in shorts

    int beg = row_ptr[node];
    int end = row_end[node];

    float acc0 = 0.0f, acc1 = 0.0f, acc2 = 0.0f, acc3 = 0.0f;

    for (int chunk = beg; chunk < end; chunk += 16) {
        int idx = chunk + l16;
        int2 pv = (idx < end) ? csr[idx] : make_int2(0, 0);
        int navail = end - chunk;
        if (navail > 16) navail = 16;
        for (int t = 0; t < navail; t += 4) {
            #pragma unroll
            for (int k = 0; k < 4; ++k) {
                int sub = t + k;                       // always <= 15
                int   cc = __shfl(pv.x, sub, 16);
                float vv = __int_as_float(__shfl(pv.y, sub, 16));
                float w  = (sub < navail) ? vv : 0.0f;
                unsigned int off = ((unsigned int)cc << 6) + fo;
                uint2 hv = *(const uint2*)&hsrc[off];
                acc0 += w * __uint_as_float((hv.x & 0xFFFFu) << 16);
                acc1 += w * __uint_as_float(hv.x & 0xFFFF0000u);
                acc2 += w * __uint_as_float((hv.y & 0xFFFFu) << 16);
                acc3 += w * __uint_as_float(hv.y & 0xFFFF0000u);
            }
        }
    }

    // epilogue: every lane stores its 4 feats (256B f32 + 128B bf16 per node)
    float di = dinv[node];
    float aL = a_vals[L];
    float s1 = aL * di;          // out scale
    float s2 = s1 * di;          // next-shadow scale
    f32x4 r = {s1 * acc0, s1 * acc1, s1 * acc2, s1 * acc3};
    __builtin_nontemporal_store(
        r, (f32x4*)&out[(size_t)node * OUT_STRIDE + L * D_FEAT + fo]);
    if (write_hdst) {
        uint2 o;
        o.x = bf16_rne(s2 * acc0) | (bf16_rne(s2 * acc1) << 16);
        o.y = bf16_rne(s2 * acc2) | (bf16_rne(s2 * acc3) << 16);
        *(uint2*)&hdst[(size_t)node * D_FEAT + fo] = o;
    }
}

// 5b. fallback fp32-source gather (used only if ws too small for shadows).
//     csr holds raw w -> needs dinv[c] gather + dinv_i epilogue scale.
__global__ void spmm_f32_kernel(const int* __restrict__ row_ptr,
                                const int* __restrict__ row_end,
                                const int2* __restrict__ csr,
                                const float* __restrict__ a_vals,
                                const float* __restrict__ dinv,
                                float* __restrict__ out,
                                int L) {
    int node = blockIdx.x * (blockDim.x >> 6) + (threadIdx.x >> 6);
    int lane = threadIdx.x & 63;
    if (node >= N_NODE) return;
    int beg = row_ptr[node];
    int end = row_end[node];
    int g = lane >> 4;
    int q = lane & 15;
    int src_base = (L - 1) * D_FEAT + (q << 2);

    float4 acc = make_float4(0.0f, 0.0f, 0.0f, 0.0f);
    for (int chunk = beg; chunk < end; chunk += 64) {
        int idx = chunk + lane;
        int2 pv = (idx < end) ? csr[idx] : make_int2(0, 0);
        int navail = end - chunk;
        if (navail > 64) navail = 64;
        for (int t = 0; t < navail; t += 4) {
            int sub = t + g;
            int   cc = __shfl(pv.x, sub);
            float vv = __int_as_float(__shfl(pv.y, sub));
            bool valid = (sub < navail);
            int   c_safe = valid ? cc : 0;
            float v_safe = valid ? (vv * dinv[c_safe]) : 0.0f;
            const float4 hv =
                *(const float4*)&out[(size_t)c_safe * OUT_STRIDE + src_base];
            acc.x += v_safe * hv.x;
            acc.y += v_safe * hv.y;
            acc.z += v_safe * hv.z;
            acc.w += v_safe * hv.w;
        }
    }
    acc.x += __shfl_down(acc.x, 32);
    acc.y += __shfl_down(acc.y, 32);
    acc.z += __shfl_down(acc.z, 32);
    acc.w += __shfl_down(acc.w, 32);
    acc.x += __shfl_down(acc.x, 16);
    acc.y += __shfl_down(acc.y, 16);
    acc.z += __shfl_down(acc.z, 16);
    acc.w += __shfl_down(acc.w, 16);
    if (g == 0) {
        float s1 = a_vals[L] * dinv[node];
        float4 r = make_float4(s1 * acc.x, s1 * acc.y, s1 * acc.z, s1 * acc.w);
        *(float4*)&out[(size_t)node * OUT_STRIDE + L * D_FEAT + (q << 2)] = r;
    }
}

// ---------------------------------------------------------------------------
extern "C" void kernel_launch(void* const* d_in, const int* in_sizes, int n_in,
                              void* d_out, int out_size, void* d_ws, size_t ws_size,
                              hipStream_t stream) {
    const float* x      = (const float*)d_in[0];
    const int*   ei     = (const int*)d_in[1];   // [2, E] int32
    const float* ea     = (const float*)d_in[2];
    const float* alphas = (const float*)d_in[3];
    float*       out    = (float*)d_out;

    // workspace layout (bucket store aliases the bf16 shadows)
    int2*  csr          = (int2*)d_ws;                       // E     (12.8 MB)
    int*   row_ptr      = (int*)(csr + N_EDGE);              // N
    int*   row_end      = row_ptr + N_NODE;                  // N
    float* dinv         = (float*)(row_end + N_NODE);        // N
    int*   bucket_cursor= (int*)(dinv + N_NODE);             // NB
    int*   bucket_base  = bucket_cursor + NB;                // NB
    float* a_vals       = (float*)(bucket_base + NB);        // 4
    int2*  bucket       = (int2*)(a_vals + 4);               // NB*CAP (16.8 MB)
    unsigned short* hb0 = (unsigned short*)bucket;           // union w/ bucket
    unsigned short* hb1 = hb0 + (size_t)N_NODE * D_FEAT;

    size_t base_bytes = (size_t)((char*)bucket - (char*)d_ws);
    size_t need_bf16  = base_bytes +
        2 * (size_t)N_NODE * D_FEAT * sizeof(unsigned short);   // ~39.7 MB
    int use_bf16 = (ws_size >= need_bf16) ? 1 : 0;

    hipMemsetAsync(bucket_cursor, 0, NB * sizeof(int), stream);

    stage1_bucket<<<S1_BLOCKS, S1_BS, 0, stream>>>(ei, ea, bucket_cursor, bucket);
    bucket_scan_kernel<<<1, NB, 0, stream>>>(bucket_cursor, bucket_base,
                                             alphas, a_vals);
    stage2_fused<<<NB, 1024, 0, stream>>>(bucket, bucket_cursor, bucket_base,
                                          row_ptr, row_end, dinv, csr);
    init_out_kernel<<<(N_NODE * (D_FEAT / 4) + 255) / 256, 256, 0, stream>>>(
        x, dinv, out, hb0, use_bf16);

    if (use_bf16) {
        // L=1: src hb0 -> dst hb1 ; L=2: src hb1 -> dst hb0 ; L=3: src hb0, no dst
        spmm_bf16_kernel<<<SPMM_BLOCKS, 256, 0, stream>>>(row_ptr, row_end, csr,
            a_vals, dinv, hb0, hb1, out, 1, 1);
        spmm_bf16_kernel<<<SPMM_BLOCKS, 256, 0, stream>>>(row_ptr, row_end, csr,
            a_vals, dinv, hb1, hb0, out, 2, 1);
        spmm_bf16_kernel<<<SPMM_BLOCKS, 256, 0, stream>>>(row_ptr, row_end, csr,
            a_vals, dinv, hb0, hb1, out, 3, 0);
    } else {
        int nodes_per_block = 256 / 64;
        int spmm_blocks = (N_NODE + nodes_per_block - 1) / nodes_per_block;
        for (int L = 1; L <= DEPTH; ++L) {
            spmm_f32_kernel<<<spmm_blocks, 256, 0, stream>>>(row_ptr, row_end, csr,
                a_vals, dinv, out, L);
        }
    }
}

// Round 9
// 321.450 us; speedup vs baseline: 1.2531x; 1.0030x over previous
//
#include <hip/hip_runtime.h>
#include <math.h>

#define N_NODE 100000
#define N_EDGE 1600000
#define D_FEAT 64
#define DEPTH  3
#define OUT_STRIDE ((DEPTH + 1) * D_FEAT)   // 256 floats per node row

// ---- bucketed CSR build ----------------------------------------------------
#define NB  512                      // buckets (one stage2 block each)
#define RPB 196                      // rows per bucket: 512*196 = 100352 >= N
#define CAP 4096                     // per-bucket edge capacity (mean 3136, +17 sigma)
#define S1_BS 512
#define S1_CHUNK 8192                // edges per stage1 block
#define S1_BLOCKS ((N_EDGE + S1_CHUNK - 1) / S1_CHUNK)   // 196

// ---- lane-owns-feature spmm -------------------------------------------------
#define SPMM_NPB 16                  // nodes per 256-thread block (4/wave)
#define SPMM_BLOCKS (N_NODE / SPMM_NPB)      // 6250

// fixed-point scale for weighted-degree accumulation (ea in [0,1), deg < 128)
#define DEG_SCALE 33554432.0f        // 2^25

typedef float  f32x4 __attribute__((ext_vector_type(4)));

__device__ __forceinline__ unsigned int bf16_rne(float f) {
    unsigned int u = __float_as_uint(f);
    return (u + 0x7FFFu + ((u >> 16) & 1u)) >> 16;
}

// ---------------------------------------------------------------------------
// 1. multisplit edges into NB buckets (contiguous segment reservation).
__global__ __launch_bounds__(S1_BS) void stage1_bucket(
        const int* __restrict__ ei, const float* __restrict__ ea,
        int* __restrict__ bucket_cursor, int2* __restrict__ bucket) {
    __shared__ int hist[NB];
    __shared__ int segb[NB];
    int tid = threadIdx.x;
    int e0 = blockIdx.x * S1_CHUNK;

    for (int i = tid; i < NB; i += S1_BS) hist[i] = 0;
    __syncthreads();

    for (int k = 0; k < S1_CHUNK; k += S1_BS) {
        int e = e0 + k + tid;
        if (e < N_EDGE) {
            int r = ei[e];
            atomicAdd(&hist[r / RPB], 1);
        }
    }
    __syncthreads();

    for (int i = tid; i < NB; i += S1_BS) {
        int h = hist[i];
        segb[i] = (h > 0) ? atomicAdd(&bucket_cursor[i], h) : 0;
        hist[i] = 0;
    }
    __syncthreads();

    for (int k = 0; k < S1_CHUNK; k += S1_BS) {
        int e = e0 + k + tid;
        if (e < N_EDGE) {
            int r  = ei[e];
            int b  = r / RPB;
            int rl = r - b * RPB;         // < 196, 8 bits
            int c  = ei[N_EDGE + e];      // < 100000, 17 bits
            float w = ea[e];
            int lofs = atomicAdd(&hist[b], 1);
            int pos  = segb[b] + lofs;
            if (pos < CAP)
                bucket[(size_t)b * CAP + pos] =
                    make_int2((rl << 17) | c, __float_as_int(w));
        }
    }
}

// ---------------------------------------------------------------------------
// 2. fully-fused per-bucket build (one block per bucket):
//    - self-scan of the 512 bucket counts -> bucket base (no separate kernel)
//    - row histogram + fixed-point weighted degree (LDS atomics)
//    - 256-wide scan -> row_ptr/row_end/dinv
//    - place edges (c, raw w) at exact CSR slots in 32KB LDS, stream out
//    - fused init: copy x rows -> out[:,0,:] (nt) and write hb0 = bf16(dinv*x)
//    - block 0 computes a_vals = tanh(alphas)
//    csr keeps RAW w; dinv scaling is folded into the spmm epilogues.
__global__ __launch_bounds__(1024) void stage2_fused(
        const int2* __restrict__ bucket, const int* __restrict__ bucket_cnt,
        const float* __restrict__ x, const float* __restrict__ alphas,
        int* __restrict__ row_ptr, int* __restrict__ row_end,
        float* __restrict__ dinv_g, float* __restrict__ a_vals,
        int2* __restrict__ csr, float* __restrict__ out,
        unsigned short* __restrict__ hb0, int write_hb) {
    __shared__ int          bscan[NB];       // 2KB  bucket-count scan
    __shared__ int          rcnt[RPB];
    __shared__ unsigned int wdeg[RPB];
    __shared__ float        dinvl[RPB];
    __shared__ int          lcur[RPB];
    __shared__ int          sc[256];
    __shared__ int2         staged[CAP];     // 32KB
    int b = blockIdx.x, tid = threadIdx.x;

    // ---- bucket-base self-scan (inclusive Hillis-Steele over 512) ----
    if (tid < NB) bscan[tid] = bucket_cnt[tid];
    for (int i = tid; i < RPB; i += 1024) { rcnt[i] = 0; wdeg[i] = 0u; }
    __syncthreads();
    for (int off = 1; off < NB; off <<= 1) {
        int t = (tid < NB && tid >= off) ? bscan[tid - off] : 0;
        __syncthreads();
        if (tid < NB) bscan[tid] += t;
        __syncthreads();
    }
    int base_b = (b == 0) ? 0 : bscan[b - 1];
    int cnt    = bscan[b] - base_b;
    if (cnt > CAP) cnt = CAP;                // paranoia guard

    const int2* src = bucket + (size_t)b * CAP;

    // ---- pass 1: row histogram + weighted degree ----
    for (int i = tid; i < cnt; i += 1024) {
        int2 e = src[i];
        int rl = e.x >> 17;
        atomicAdd(&rcnt[rl], 1);
        atomicAdd(&wdeg[rl],
                  (unsigned int)(__int_as_float(e.y) * DEG_SCALE + 0.5f));
    }
    __syncthreads();

    // ---- 256-wide inclusive scan of row counts (RPB = 196 <= 256) ----
    int v = 0;
    if (tid < 256) { v = (tid < RPB) ? rcnt[tid] : 0; sc[tid] = v; }
    __syncthreads();
    for (int off = 1; off < 256; off <<= 1) {
        int t = 0;
        if (tid < 256 && tid >= off) t = sc[tid - off];
        __syncthreads();
        if (tid < 256) sc[tid] += t;
        __syncthreads();
    }

    if (tid < RPB) {
        int excl = sc[tid] - v;
        lcur[tid] = excl;
        int row = b * RPB + tid;
        float di = 0.0f;
        if (row < N_NODE) {
            row_ptr[row] = base_b + excl;
            row_end[row] = base_b + excl + rcnt[tid];
            float d = (float)wdeg[tid] * (1.0f / DEG_SCALE);
            di = (d > 0.0f) ? rsqrtf(d) : 0.0f;
            dinv_g[row] = di;
        }
        dinvl[tid] = di;
    }
    __syncthreads();

    // ---- pass 2: place edges at exact CSR slots ----
    for (int i = tid; i < cnt; i += 1024) {
        int2 e = src[i];
        int rl = e.x >> 17;
        int pos = atomicAdd(&lcur[rl], 1);
        staged[pos] = make_int2(e.x & 0x1FFFF, e.y);   // keep raw w
    }
    __syncthreads();

    // ---- stream CSR out (coalesced) ----
    for (int i = tid; i < cnt; i += 1024) csr[base_b + i] = staged[i];

    // ---- fused init for this block's rows: out[:,0,:] + hb0 shadow ----
    for (int i = tid; i < RPB * 16; i += 1024) {
        int r   = i >> 4;
        int row = b * RPB + r;
        if (row < N_NODE) {
            int d4 = (i & 15) << 2;
            float4 vx = *(const float4*)&x[(size_t)row * D_FEAT + d4];
            f32x4 vv = {vx.x, vx.y, vx.z, vx.w};
            __builtin_nontemporal_store(
                vv, (f32x4*)&out[(size_t)row * OUT_STRIDE + d4]);
            if (write_hb) {
                float s = dinvl[r];
                uint2 o;
                o.x = bf16_rne(vx.x * s) | (bf16_rne(vx.y * s) << 16);
                o.y = bf16_rne(vx.z * s) | (bf16_rne(vx.w * s) << 16);
                *(uint2*)&hb0[(size_t)row * D_FEAT + d4] = o;
            }
        }
    }

    if (b == 0 && tid < DEPTH + 1) a_vals[tid] = tanhf(alphas[tid]);
}

// ---------------------------------------------------------------------------
// 3a. lane-owns-feature gather SpMM (full D, bf16 dinv-scaled source).
//     wave = 4 nodes x 16 lanes; lane owns feats [4*l16 .. 4*l16+3] (uint2).
//     Per edge: 2 width-16 shuffles broadcast (c,w); each lane issues one
//     independent 8B gather -> 16 lanes cover the 128B row exactly; no
//     cross-lane reduction at all.
//     out_L[i] = aL*dinv_i * sum w_e*g[col_e];  g_L[i] = dinv_i*out_L[i]
__global__ __launch_bounds__(256) void spmm_bf16_kernel(
        const int* __restrict__ row_ptr,
        const int* __restrict__ row_end,
        const int2* __restrict__ csr,
        const float* __restrict__ a_vals,
        const float* __restrict__ dinv,
        const unsigned short* __restrict__ hsrc,
        unsigned short* __restrict__ hdst,
        float* __restrict__ out,
        int L, int write_hdst) {
    int wid  = threadIdx.x >> 6;              // wave 0..3
    int lane = threadIdx.x & 63;
    int grp  = lane >> 4;                     // node sub-index 0..3
    int l16  = lane & 15;                     // feature quad 0..15
    int node = blockIdx.x * SPMM_NPB + wid * 4 + grp;
    unsigned int fo = (unsigned int)(l16 << 2);   // feat offset in shorts

    int beg = row_ptr[node];
    int end = row_end[node];

    float acc0 = 0.0f, acc1 = 0.0f, acc2 = 0.0f, acc3 = 0.0f;

    for (int chunk = beg; chunk < end; chunk += 16) {
        int idx = chunk + l16;
        int2 pv = (idx < end) ? csr[idx] : make_int2(0, 0);
        int navail = end - chunk;
        if (navail > 16) navail = 16;
        for (int t = 0; t < navail; t += 4) {
            #pragma unroll
            for (int k = 0; k < 4; ++k) {
                int sub = t + k;                       // always <= 15
                int   cc = __shfl(pv.x, sub, 16);
                float vv = __int_as_float(__shfl(pv.y, sub, 16));
                float w  = (sub < navail) ? vv : 0.0f;
                unsigned int off = ((unsigned int)cc << 6) + fo;
                uint2 hv = *(const uint2*)&hsrc[off];
                acc0 += w * __uint_as_float((hv.x & 0xFFFFu) << 16);
                acc1 += w * __uint_as_float(hv.x & 0xFFFF0000u);
                acc2 += w * __uint_as_float((hv.y & 0xFFFFu) << 16);
                acc3 += w * __uint_as_float(hv.y & 0xFFFF0000u);
            }
        }
    }

    // epilogue: every lane stores its 4 feats (256B f32 + 128B bf16 per node)
    float di = dinv[node];
    float aL = a_vals[L];
    float s1 = aL * di;          // out scale
    float s2 = s1 * di;          // next-shadow scale
    f32x4 r = {s1 * acc0, s1 * acc1, s1 * acc2, s1 * acc3};
    __builtin_nontemporal_store(
        r, (f32x4*)&out[(size_t)node * OUT_STRIDE + L * D_FEAT + fo]);
    if (write_hdst) {
        uint2 o;
        o.x = bf16_rne(s2 * acc0) | (bf16_rne(s2 * acc1) << 16);
        o.y = bf16_rne(s2 * acc2) | (bf16_rne(s2 * acc3) << 16);
        *(uint2*)&hdst[(size_t)node * D_FEAT + fo] = o;
    }
}

// 3b. fallback fp32-source gather (used only if ws too small for shadows).
//     csr holds raw w -> needs dinv[c] gather + dinv_i epilogue scale.
__global__ void spmm_f32_kernel(const int* __restrict__ row_ptr,
                                const int* __restrict__ row_end,
                                const int2* __restrict__ csr,
                                const float* __restrict__ a_vals,
                                const float* __restrict__ dinv,
                                float* __restrict__ out,
                                int L) {
    int node = blockIdx.x * (blockDim.x >> 6) + (threadIdx.x >> 6);
    int lane = threadIdx.x & 63;
    if (node >= N_NODE) return;
    int beg = row_ptr[node];
    int end = row_end[node];
    int g = lane >> 4;
    int q = lane & 15;
    int src_base = (L - 1) * D_FEAT + (q << 2);

    float4 acc = make_float4(0.0f, 0.0f, 0.0f, 0.0f);
    for (int chunk = beg; chunk < end; chunk += 64) {
        int idx = chunk + lane;
        int2 pv = (idx < end) ? csr[idx] : make_int2(0, 0);
        int navail = end - chunk;
        if (navail > 64) navail = 64;
        for (int t = 0; t < navail; t += 4) {
            int sub = t + g;
            int   cc = __shfl(pv.x, sub);
            float vv = __int_as_float(__shfl(pv.y, sub));
            bool valid = (sub < navail);
            int   c_safe = valid ? cc : 0;
            float v_safe = valid ? (vv * dinv[c_safe]) : 0.0f;
            const float4 hv =
                *(const float4*)&out[(size_t)c_safe * OUT_STRIDE + src_base];
            acc.x += v_safe * hv.x;
            acc.y += v_safe * hv.y;
            acc.z += v_safe * hv.z;
            acc.w += v_safe * hv.w;
        }
    }
    acc.x += __shfl_down(acc.x, 32);
    acc.y += __shfl_down(acc.y, 32);
    acc.z += __shfl_down(acc.z, 32);
    acc.w += __shfl_down(acc.w, 32);
    acc.x += __shfl_down(acc.x, 16);
    acc.y += __shfl_down(acc.y, 16);
    acc.z += __shfl_down(acc.z, 16);
    acc.w += __shfl_down(acc.w, 16);
    if (g == 0) {
        float s1 = a_vals[L] * dinv[node];
        float4 r = make_float4(s1 * acc.x, s1 * acc.y, s1 * acc.z, s1 * acc.w);
        *(float4*)&out[(size_t)node * OUT_STRIDE + L * D_FEAT + (q << 2)] = r;
    }
}

// ---------------------------------------------------------------------------
extern "C" void kernel_launch(void* const* d_in, const int* in_sizes, int n_in,
                              void* d_out, int out_size, void* d_ws, size_t ws_size,
                              hipStream_t stream) {
    const float* x      = (const float*)d_in[0];
    const int*   ei     = (const int*)d_in[1];   // [2, E] int32
    const float* ea     = (const float*)d_in[2];
    const float* alphas = (const float*)d_in[3];
    float*       out    = (float*)d_out;

    // workspace layout (no aliasing; ~57 MB total)
    int2*  csr          = (int2*)d_ws;                       // E     (12.8 MB)
    int*   row_ptr      = (int*)(csr + N_EDGE);              // N
    int*   row_end      = row_ptr + N_NODE;                  // N
    float* dinv         = (float*)(row_end + N_NODE);        // N
    int*   bucket_cursor= (int*)(dinv + N_NODE);             // NB
    float* a_vals       = (float*)(bucket_cursor + NB);      // 4
    int2*  bucket       = (int2*)(a_vals + 4);               // NB*CAP (16.8 MB)
    unsigned short* hb0 = (unsigned short*)(bucket + (size_t)NB * CAP);
    unsigned short* hb1 = hb0 + (size_t)N_NODE * D_FEAT;

    size_t need = (size_t)((char*)hb1 - (char*)d_ws) +
                  (size_t)N_NODE * D_FEAT * sizeof(unsigned short);
    int use_bf16 = (ws_size >= need) ? 1 : 0;

    hipMemsetAsync(bucket_cursor, 0, NB * sizeof(int), stream);

    stage1_bucket<<<S1_BLOCKS, S1_BS, 0, stream>>>(ei, ea, bucket_cursor, bucket);
    stage2_fused<<<NB, 1024, 0, stream>>>(bucket, bucket_cursor, x, alphas,
                                          row_ptr, row_end, dinv, a_vals,
                                          csr, out, hb0, use_bf16);

    if (use_bf16) {
        // L=1: src hb0 -> dst hb1 ; L=2: src hb1 -> dst hb0 ; L=3: src hb0, no dst
        spmm_bf16_kernel<<<SPMM_BLOCKS, 256, 0, stream>>>(row_ptr, row_end, csr,
            a_vals, dinv, hb0, hb1, out, 1, 1);
        spmm_bf16_kernel<<<SPMM_BLOCKS, 256, 0, stream>>>(row_ptr, row_end, csr,
            a_vals, dinv, hb1, hb0, out, 2, 1);
        spmm_bf16_kernel<<<SPMM_BLOCKS, 256, 0, stream>>>(row_ptr, row_end, csr,
            a_vals, dinv, hb0, hb1, out, 3, 0);
    } else {
        int nodes_per_block = 256 / 64;
        int spmm_blocks = (N_NODE + nodes_per_block - 1) / nodes_per_block;
        for (int L = 1; L <= DEPTH; ++L) {
            spmm_f32_kernel<<<spmm_blocks, 256, 0, stream>>>(row_ptr, row_end, csr,
                a_vals, dinv, out, L);
        }
    }
}

// Round 10
// 321.194 us; speedup vs baseline: 1.2541x; 1.0008x over previous
//
#include <hip/hip_runtime.h>
#include <math.h>

#define N_NODE 100000
#define N_EDGE 1600000
#define D_FEAT 64
#define DEPTH  3
#define OUT_STRIDE ((DEPTH + 1) * D_FEAT)   // 256 floats per node row

// ---- bucketed CSR build ----------------------------------------------------
#define NB  512                      // buckets (one stage2 block each)
#define RPB 196                      // rows per bucket: 512*196 = 100352 >= N
#define CAP 4096                     // per-bucket edge capacity (mean 3136, +17 sigma)
#define S1_BS 512
#define S1_CHUNK 8192                // edges per stage1 block
#define S1_BLOCKS ((N_EDGE + S1_CHUNK - 1) / S1_CHUNK)   // 196

// ---- lane-owns-feature spmm -------------------------------------------------
#define SPMM_NPB 16                  // nodes per 256-thread block (4/wave)
#define SPMM_BLOCKS (N_NODE / SPMM_NPB)      // 6250

// fixed-point scale for weighted-degree accumulation (ea in [0,1), deg < 128)
#define DEG_SCALE 33554432.0f        // 2^25

typedef float  f32x4 __attribute__((ext_vector_type(4)));

__device__ __forceinline__ unsigned int bf16_rne(float f) {
    unsigned int u = __float_as_uint(f);
    return (u + 0x7FFFu + ((u >> 16) & 1u)) >> 16;
}

// ---------------------------------------------------------------------------
// 1. multisplit edges into NB buckets (contiguous segment reservation).
__global__ __launch_bounds__(S1_BS) void stage1_bucket(
        const int* __restrict__ ei, const float* __restrict__ ea,
        int* __restrict__ bucket_cursor, int2* __restrict__ bucket) {
    __shared__ int hist[NB];
    __shared__ int segb[NB];
    int tid = threadIdx.x;
    int e0 = blockIdx.x * S1_CHUNK;

    for (int i = tid; i < NB; i += S1_BS) hist[i] = 0;
    __syncthreads();

    for (int k = 0; k < S1_CHUNK; k += S1_BS) {
        int e = e0 + k + tid;
        if (e < N_EDGE) {
            int r = ei[e];
            atomicAdd(&hist[r / RPB], 1);
        }
    }
    __syncthreads();

    for (int i = tid; i < NB; i += S1_BS) {
        int h = hist[i];
        segb[i] = (h > 0) ? atomicAdd(&bucket_cursor[i], h) : 0;
        hist[i] = 0;
    }
    __syncthreads();

    for (int k = 0; k < S1_CHUNK; k += S1_BS) {
        int e = e0 + k + tid;
        if (e < N_EDGE) {
            int r  = ei[e];
            int b  = r / RPB;
            int rl = r - b * RPB;         // < 196, 8 bits
            int c  = ei[N_EDGE + e];      // < 100000, 17 bits
            float w = ea[e];
            int lofs = atomicAdd(&hist[b], 1);
            int pos  = segb[b] + lofs;
            if (pos < CAP)
                bucket[(size_t)b * CAP + pos] =
                    make_int2((rl << 17) | c, __float_as_int(w));
        }
    }
}

// ---------------------------------------------------------------------------
// 2. fully-fused per-bucket build (one block per bucket): self-scan of bucket
//    counts, row histogram + weighted degree, scan -> row_ptr/row_end/dinv,
//    exact-slot placement via 32KB LDS, coalesced CSR streamout, fused
//    out[:,0,:] copy + hb0 shadow, a_vals on block 0.
__global__ __launch_bounds__(1024) void stage2_fused(
        const int2* __restrict__ bucket, const int* __restrict__ bucket_cnt,
        const float* __restrict__ x, const float* __restrict__ alphas,
        int* __restrict__ row_ptr, int* __restrict__ row_end,
        float* __restrict__ dinv_g, float* __restrict__ a_vals,
        int2* __restrict__ csr, float* __restrict__ out,
        unsigned short* __restrict__ hb0, int write_hb) {
    __shared__ int          bscan[NB];       // 2KB  bucket-count scan
    __shared__ int          rcnt[RPB];
    __shared__ unsigned int wdeg[RPB];
    __shared__ float        dinvl[RPB];
    __shared__ int          lcur[RPB];
    __shared__ int          sc[256];
    __shared__ int2         staged[CAP];     // 32KB
    int b = blockIdx.x, tid = threadIdx.x;

    // ---- bucket-base self-scan (inclusive Hillis-Steele over 512) ----
    if (tid < NB) bscan[tid] = bucket_cnt[tid];
    for (int i = tid; i < RPB; i += 1024) { rcnt[i] = 0; wdeg[i] = 0u; }
    __syncthreads();
    for (int off = 1; off < NB; off <<= 1) {
        int t = (tid < NB && tid >= off) ? bscan[tid - off] : 0;
        __syncthreads();
        if (tid < NB) bscan[tid] += t;
        __syncthreads();
    }
    int base_b = (b == 0) ? 0 : bscan[b - 1];
    int cnt    = bscan[b] - base_b;
    if (cnt > CAP) cnt = CAP;                // paranoia guard

    const int2* src = bucket + (size_t)b * CAP;

    // ---- pass 1: row histogram + weighted degree ----
    for (int i = tid; i < cnt; i += 1024) {
        int2 e = src[i];
        int rl = e.x >> 17;
        atomicAdd(&rcnt[rl], 1);
        atomicAdd(&wdeg[rl],
                  (unsigned int)(__int_as_float(e.y) * DEG_SCALE + 0.5f));
    }
    __syncthreads();

    // ---- 256-wide inclusive scan of row counts (RPB = 196 <= 256) ----
    int v = 0;
    if (tid < 256) { v = (tid < RPB) ? rcnt[tid] : 0; sc[tid] = v; }
    __syncthreads();
    for (int off = 1; off < 256; off <<= 1) {
        int t = 0;
        if (tid < 256 && tid >= off) t = sc[tid - off];
        __syncthreads();
        if (tid < 256) sc[tid] += t;
        __syncthreads();
    }

    if (tid < RPB) {
        int excl = sc[tid] - v;
        lcur[tid] = excl;
        int row = b * RPB + tid;
        float di = 0.0f;
        if (row < N_NODE) {
            row_ptr[row] = base_b + excl;
            row_end[row] = base_b + excl + rcnt[tid];
            float d = (float)wdeg[tid] * (1.0f / DEG_SCALE);
            di = (d > 0.0f) ? rsqrtf(d) : 0.0f;
            dinv_g[row] = di;
        }
        dinvl[tid] = di;
    }
    __syncthreads();

    // ---- pass 2: place edges at exact CSR slots ----
    for (int i = tid; i < cnt; i += 1024) {
        int2 e = src[i];
        int rl = e.x >> 17;
        int pos = atomicAdd(&lcur[rl], 1);
        staged[pos] = make_int2(e.x & 0x1FFFF, e.y);   // keep raw w
    }
    __syncthreads();

    // ---- stream CSR out (coalesced) ----
    for (int i = tid; i < cnt; i += 1024) csr[base_b + i] = staged[i];

    // ---- fused init for this block's rows: out[:,0,:] + hb0 shadow ----
    for (int i = tid; i < RPB * 16; i += 1024) {
        int r   = i >> 4;
        int row = b * RPB + r;
        if (row < N_NODE) {
            int d4 = (i & 15) << 2;
            float4 vx = *(const float4*)&x[(size_t)row * D_FEAT + d4];
            f32x4 vv = {vx.x, vx.y, vx.z, vx.w};
            __builtin_nontemporal_store(
                vv, (f32x4*)&out[(size_t)row * OUT_STRIDE + d4]);
            if (write_hb) {
                float s = dinvl[r];
                uint2 o;
                o.x = bf16_rne(vx.x * s) | (bf16_rne(vx.y * s) << 16);
                o.y = bf16_rne(vx.z * s) | (bf16_rne(vx.w * s) << 16);
                *(uint2*)&hb0[(size_t)row * D_FEAT + d4] = o;
            }
        }
    }

    if (b == 0 && tid < DEPTH + 1) a_vals[tid] = tanhf(alphas[tid]);
}

// ---------------------------------------------------------------------------
// 3a. lane-owns-feature gather SpMM, batched-issue inner loop.
//     wave = 4 nodes x 16 lanes; lane owns feats [4*l16 .. 4*l16+3] (uint2).
//     Per 16-edge chunk: broadcast all 16 (c,w) then issue ALL 16 gathers
//     before any FMA -> 16 outstanding loads/lane (vs 4). Lanes past the
//     row end carry pv=(0,0): w=0, c=0 -> padded gathers hit row 0 (L1-hot),
//     so no navail clamp or per-edge branch is needed.
//     out_L[i] = aL*dinv_i * sum w_e*g[col_e];  g_L[i] = dinv_i*out_L[i]
__global__ __launch_bounds__(256) void spmm_bf16_kernel(
        const int* __restrict__ row_ptr,
        const int* __restrict__ row_end,
        const int2* __restrict__ csr,
        const float* __restrict__ a_vals,
        const float* __restrict__ dinv,
        const unsigned short* __restrict__ hsrc,
        unsigned short* __restrict__ hdst,
        float* __restrict__ out,
        int L, int write_hdst) {
    int wid  = threadIdx.x >> 6;              // wave 0..3
    int lane = threadIdx.x & 63;
    int grp  = lane >> 4;                     // node sub-index 0..3
    int l16  = lane & 15;                     // feature quad 0..15
    int node = blockIdx.x * SPMM_NPB + wid * 4 + grp;
    unsigned int fo = (unsigned int)(l16 << 2);   // feat offset in shorts

    int beg = row_ptr[node];
    int end = row_end[node];

    float acc0 = 0.0f, acc1 = 0.0f, acc2 = 0.0f, acc3 = 0.0f;

    for (int chunk = beg; chunk < end; chunk += 16) {
        int idx = chunk + l16;
        int2 pv = (idx < end) ? csr[idx] : make_int2(0, 0);
        uint2 hv[16];
        float wv[16];
        #pragma unroll
        for (int k = 0; k < 16; ++k) {
            int cc = __shfl(pv.x, k, 16);
            wv[k]  = __int_as_float(__shfl(pv.y, k, 16));
            hv[k]  = *(const uint2*)&hsrc[(((unsigned int)cc) << 6) + fo];
        }
        #pragma unroll
        for (int k = 0; k < 16; ++k) {
            float w = wv[k];
            acc0 += w * __uint_as_float((hv[k].x & 0xFFFFu) << 16);
            acc1 += w * __uint_as_float(hv[k].x & 0xFFFF0000u);
            acc2 += w * __uint_as_float((hv[k].y & 0xFFFFu) << 16);
            acc3 += w * __uint_as_float(hv[k].y & 0xFFFF0000u);
        }
    }

    // epilogue: every lane stores its 4 feats (256B f32 + 128B bf16 per node)
    float di = dinv[node];
    float aL = a_vals[L];
    float s1 = aL * di;          // out scale
    float s2 = s1 * di;          // next-shadow scale
    f32x4 r = {s1 * acc0, s1 * acc1, s1 * acc2, s1 * acc3};
    __builtin_nontemporal_store(
        r, (f32x4*)&out[(size_t)node * OUT_STRIDE + L * D_FEAT + fo]);
    if (write_hdst) {
        uint2 o;
        o.x = bf16_rne(s2 * acc0) | (bf16_rne(s2 * acc1) << 16);
        o.y = bf16_rne(s2 * acc2) | (bf16_rne(s2 * acc3) << 16);
        *(uint2*)&hdst[(size_t)node * D_FEAT + fo] = o;
    }
}

// 3b. fallback fp32-source gather (used only if ws too small for shadows).
//     csr holds raw w -> needs dinv[c] gather + dinv_i epilogue scale.
__global__ void spmm_f32_kernel(const int* __restrict__ row_ptr,
                                const int* __restrict__ row_end,
                                const int2* __restrict__ csr,
                                const float* __restrict__ a_vals,
                                const float* __restrict__ dinv,
                                float* __restrict__ out,
                                int L) {
    int node = blockIdx.x * (blockDim.x >> 6) + (threadIdx.x >> 6);
    int lane = threadIdx.x & 63;
    if (node >= N_NODE) return;
    int beg = row_ptr[node];
    int end = row_end[node];
    int g = lane >> 4;
    int q = lane & 15;
    int src_base = (L - 1) * D_FEAT + (q << 2);

    float4 acc = make_float4(0.0f, 0.0f, 0.0f, 0.0f);
    for (int chunk = beg; chunk < end; chunk += 64) {
        int idx = chunk + lane;
        int2 pv = (idx < end) ? csr[idx] : make_int2(0, 0);
        int navail = end - chunk;
        if (navail > 64) navail = 64;
        for (int t = 0; t < navail; t += 4) {
            int sub = t + g;
            int   cc = __shfl(pv.x, sub);
            float vv = __int_as_float(__shfl(pv.y, sub));
            bool valid = (sub < navail);
            int   c_safe = valid ? cc : 0;
            float v_safe = valid ? (vv * dinv[c_safe]) : 0.0f;
            const float4 hv =
                *(const float4*)&out[(size_t)c_safe * OUT_STRIDE + src_base];
            acc.x += v_safe * hv.x;
            acc.y += v_safe * hv.y;
            acc.z += v_safe * hv.z;
            acc.w += v_safe * hv.w;
        }
    }
    acc.x += __shfl_down(acc.x, 32);
    acc.y += __shfl_down(acc.y, 32);
    acc.z += __shfl_down(acc.z, 32);
    acc.w += __shfl_down(acc.w, 32);
    acc.x += __shfl_down(acc.x, 16);
    acc.y += __shfl_down(acc.y, 16);
    acc.z += __shfl_down(acc.z, 16);
    acc.w += __shfl_down(acc.w, 16);
    if (g == 0) {
        float s1 = a_vals[L] * dinv[node];
        float4 r = make_float4(s1 * acc.x, s1 * acc.y, s1 * acc.z, s1 * acc.w);
        *(float4*)&out[(size_t)node * OUT_STRIDE + L * D_FEAT + (q << 2)] = r;
    }
}

// ---------------------------------------------------------------------------
extern "C" void kernel_launch(void* const* d_in, const int* in_sizes, int n_in,
                              void* d_out, int out_size, void* d_ws, size_t ws_size,
                              hipStream_t stream) {
    const float* x      = (const float*)d_in[0];
    const int*   ei     = (const int*)d_in[1];   // [2, E] int32
    const float* ea     = (const float*)d_in[2];
    const float* alphas = (const float*)d_in[3];
    float*       out    = (float*)d_out;

    // workspace layout (no aliasing; ~57 MB total)
    int2*  csr          = (int2*)d_ws;                       // E     (12.8 MB)
    int*   row_ptr      = (int*)(csr + N_EDGE);              // N
    int*   row_end      = row_ptr + N_NODE;                  // N
    float* dinv         = (float*)(row_end + N_NODE);        // N
    int*   bucket_cursor= (int*)(dinv + N_NODE);             // NB
    float* a_vals       = (float*)(bucket_cursor + NB);      // 4
    int2*  bucket       = (int2*)(a_vals + 4);               // NB*CAP (16.8 MB)
    unsigned short* hb0 = (unsigned short*)(bucket + (size_t)NB * CAP);
    unsigned short* hb1 = hb0 + (size_t)N_NODE * D_FEAT;

    size_t need = (size_t)((char*)hb1 - (char*)d_ws) +
                  (size_t)N_NODE * D_FEAT * sizeof(unsigned short);
    int use_bf16 = (ws_size >= need) ? 1 : 0;

    hipMemsetAsync(bucket_cursor, 0, NB * sizeof(int), stream);

    stage1_bucket<<<S1_BLOCKS, S1_BS, 0, stream>>>(ei, ea, bucket_cursor, bucket);
    stage2_fused<<<NB, 1024, 0, stream>>>(bucket, bucket_cursor, x, alphas,
                                          row_ptr, row_end, dinv, a_vals,
                                          csr, out, hb0, use_bf16);

    if (use_bf16) {
        // L=1: src hb0 -> dst hb1 ; L=2: src hb1 -> dst hb0 ; L=3: src hb0, no dst
        spmm_bf16_kernel<<<SPMM_BLOCKS, 256, 0, stream>>>(row_ptr, row_end, csr,
            a_vals, dinv, hb0, hb1, out, 1, 1);
        spmm_bf16_kernel<<<SPMM_BLOCKS, 256, 0, stream>>>(row_ptr, row_end, csr,
            a_vals, dinv, hb1, hb0, out, 2, 1);
        spmm_bf16_kernel<<<SPMM_BLOCKS, 256, 0, stream>>>(row_ptr, row_end, csr,
            a_vals, dinv, hb0, hb1, out, 3, 0);
    } else {
        int nodes_per_block = 256 / 64;
        int spmm_blocks = (N_NODE + nodes_per_block - 1) / nodes_per_block;
        for (int L = 1; L <= DEPTH; ++L) {
            spmm_f32_kernel<<<spmm_blocks, 256, 0, stream>>>(row_ptr, row_end, csr,
                a_vals, dinv, out, L);
        }
    }
}